// Round 13
// baseline (313.122 us; speedup 1.0000x reference)
//
#include <hip/hip_runtime.h>

typedef __bf16 bf16;
typedef __bf16 bf16x2 __attribute__((ext_vector_type(2)));
typedef __bf16 bf16x4 __attribute__((ext_vector_type(4)));
typedef __bf16 bf16x8 __attribute__((ext_vector_type(8)));
typedef float f32x4 __attribute__((ext_vector_type(4)));
typedef float f32x16 __attribute__((ext_vector_type(16)));

#define S_LEN 2048
#define HID_DIM 4096
#define NH 32
#define NKV 8
#define HD 128
#define QKV_N 6144   // 4096 Q + 1024 K + 1024 V
#define K_COL 4096
#define V_COL 5120
#define PADV 76

// ------- fused fp32->bf16 conversion + RoPE tables (float2 cos,sin) -------
// Wq/Wk rows PERMUTED so RoPE pairs (d,d+64) land in adjacent qkv columns.
__global__ void cvt_all_kernel(const float* __restrict__ hs, const float* __restrict__ wq,
                               const float* __restrict__ wk, const float* __restrict__ wv,
                               const float* __restrict__ wo, bf16* __restrict__ hsb,
                               bf16* __restrict__ wqkvb, bf16* __restrict__ wob,
                               float2* __restrict__ csf) {
  long i = (long)blockIdx.x * blockDim.x + threadIdx.x;
  if (i >= 12582912) {                   // RoPE tables: 2048*64 entries
    int j = (int)(i - 12582912);
    int s = j >> 6, d = j & 63;
    float inv = expf(-0.14391156831212787f * (float)d);   // 10000^(-d/64)
    float ang = (float)s * inv;
    csf[j] = make_float2(cosf(ang), sinf(ang));
    return;
  }
  const float* src; bf16* dst; long off; bool perm = false;
  if (i < 2097152)      { src = hs; dst = hsb;                          off = i; }
  else if (i < 6291456) { src = wq; dst = wqkvb;                        off = i - 2097152; perm = true; }
  else if (i < 7340032) { src = wk; dst = wqkvb + (long)4096 * 4096;    off = i - 6291456; perm = true; }
  else if (i < 8388608) { src = wv; dst = wqkvb + (long)5120 * 4096;    off = i - 7340032; }
  else                  { src = wo; dst = wob;                          off = i - 8388608; }
  float4 v = reinterpret_cast<const float4*>(src)[off];
  bf16x4 o;
  o[0] = (bf16)v.x; o[1] = (bf16)v.y; o[2] = (bf16)v.z; o[3] = (bf16)v.w;
  long doff = off;
  if (perm) {
    long r = off >> 10, c4 = off & 1023;
    long d = r & 127;
    long pd = ((d & 63) << 1) | (d >> 6);
    doff = (((r & ~127L) | pd) << 10) | c4;
  }
  reinterpret_cast<bf16x4*>(dst)[doff] = o;
}

// ---- 4-phase GEMM: BM=256, BN=NB*64, BK=64 (R8 schedule) + optional fused RoPE ----
#define STG8(buf, mat, kt, unit) {                                                       \
    const bf16* sp_ = (mat) ? Bp : Ap;                                                   \
    int row0_ = ((mat) ? n0 : m0) + (unit) * 64;                                         \
    int lb_ = (buf) * LBUF + (mat) * 16384 + (unit) * 4096;                              \
    int r_ = t >> 3, jl_ = t & 7, jg_ = jl_ ^ (r_ & 7);                                  \
    const bf16* src_ = sp_ + (long)(row0_ + r_) * K + (kt) * 64 + jg_ * 8;               \
    __builtin_amdgcn_global_load_lds((const __attribute__((address_space(1))) void*)src_,\
        (__attribute__((address_space(3))) void*)(L + lb_ + t * 8), 16, 0, 0); }

#define DSA2(buf, mh) {                                                                  \
    _Pragma("unroll") for (int ks_ = 0; ks_ < 2; ++ks_)                                  \
      _Pragma("unroll") for (int mf_ = 0; mf_ < 4; ++mf_) {                              \
        int R_ = wr * 128 + (mh) * 64 + mf_ * 16 + lm;                                   \
        aF[ks_][mf_] = *reinterpret_cast<const bf16x8*>(                                 \
            L + (buf) * LBUF + R_ * 64 + (((ks_ * 4 + lg) ^ (R_ & 7)) << 3));            \
      } }

#define DSBALL(buf) {                                                                    \
    _Pragma("unroll") for (int ks_ = 0; ks_ < 2; ++ks_)                                  \
      _Pragma("unroll") for (int nf_ = 0; nf_ < NB; ++nf_) {                             \
        int R_ = wc * (NB * 16) + nf_ * 16 + lm;                                         \
        bF[ks_][nf_] = *reinterpret_cast<const bf16x8*>(                                 \
            L + (buf) * LBUF + 16384 + R_ * 64 + (((ks_ * 4 + lg) ^ (R_ & 7)) << 3));    \
      } }

#define MM2(mh) {                                                                        \
    __builtin_amdgcn_s_setprio(1);                                                       \
    _Pragma("unroll") for (int mf_ = 0; mf_ < 4; ++mf_)                                  \
      _Pragma("unroll") for (int nf_ = 0; nf_ < NB; ++nf_)                               \
        _Pragma("unroll") for (int ks_ = 0; ks_ < 2; ++ks_)                              \
          acc[(mh) * 4 + mf_][nf_] = __builtin_amdgcn_mfma_f32_16x16x32_bf16(            \
              aF[ks_][mf_], bF[ks_][nf_], acc[(mh) * 4 + mf_][nf_], 0, 0, 0);            \
    __builtin_amdgcn_s_setprio(0); }

#define BAR() __builtin_amdgcn_s_barrier()
#define WVM(n) asm volatile("s_waitcnt vmcnt(%0)" :: "i"(n) : "memory")

template<int NB, bool ROPE, typename OutT>
__global__ __launch_bounds__(512, 1) void gemm4p_kernel(
    const bf16* __restrict__ Ap, const bf16* __restrict__ Bp, OutT* __restrict__ C,
    int M, int N, int K, const float2* __restrict__ csf) {
  constexpr int LBUF = 16384 + NB * 4096;
  __shared__ __align__(16) bf16 L[2 * LBUF];

  int nwg = gridDim.x * gridDim.y;
  int bid = blockIdx.y * gridDim.x + blockIdx.x;
  int cpx = nwg >> 3;
  int swz = (bid & 7) * cpx + (bid >> 3);
  int bxs = swz % gridDim.x, bys = swz / gridDim.x;
  const int n0 = bxs * (NB * 64), m0 = bys * 256;

  const int t = threadIdx.x;
  const int lane = t & 63, w = t >> 6;
  const int wr = w >> 2, wc = w & 3;
  const int lg = lane >> 4, lm = lane & 15;
  const int NT = K >> 6;

  f32x4 acc[8][NB] = {};
  bf16x8 aF[2][4], bF[2][NB];

  STG8(0, 0, 0, 0); STG8(0, 0, 0, 1); STG8(0, 0, 0, 2); STG8(0, 0, 0, 3);
  STG8(0, 1, 0, 0); if (NB > 1) STG8(0, 1, 0, 1); if (NB > 2) STG8(0, 1, 0, 2);
  STG8(1, 1, 1, 0); if (NB > 1) STG8(1, 1, 1, 1); if (NB > 2) STG8(1, 1, 1, 2);
  WVM(NB);
  BAR();

  for (int I = 0; I < (NT >> 1); ++I) {
    const int tt = 2 * I;
    const bool pf = (I < (NT >> 1) - 1);
    DSA2(0, 0); DSBALL(0);
    STG8(1, 0, tt + 1, 0); STG8(1, 0, tt + 1, 1);
    STG8(1, 0, tt + 1, 2); STG8(1, 0, tt + 1, 3);
    BAR(); MM2(0); BAR();
    DSA2(0, 1);
    if (pf) { STG8(0, 1, tt + 2, 0); if (NB > 1) STG8(0, 1, tt + 2, 1);
              if (NB > 2) STG8(0, 1, tt + 2, 2); }
    BAR(); MM2(1);
    if (pf) WVM(NB); else WVM(0);
    BAR();
    DSA2(1, 0); DSBALL(1);
    if (pf) { STG8(0, 0, tt + 2, 0); STG8(0, 0, tt + 2, 1);
              STG8(0, 0, tt + 2, 2); STG8(0, 0, tt + 2, 3); }
    BAR(); MM2(0); BAR();
    DSA2(1, 1);
    if (pf) { STG8(1, 1, tt + 3, 0); if (NB > 1) STG8(1, 1, tt + 3, 1);
              if (NB > 2) STG8(1, 1, tt + 3, 2); }
    BAR(); MM2(1);
    if (pf) WVM(NB); else WVM(0);
    BAR();
  }

  // ---- epilogue (optionally fused RoPE for Q/K columns) ----
#pragma unroll
  for (int am = 0; am < 8; ++am) {
    int row = m0 + wr * 128 + am * 16 + lg * 4;
#pragma unroll
    for (int nf = 0; nf < NB; ++nf) {
      int col = n0 + wc * (NB * 16) + nf * 16 + lm;
      if (ROPE && col < V_COL) {
        int j = (col & 127) >> 1;
        bool odd = col & 1;
#pragma unroll
        for (int rr = 0; rr < 4; ++rr) {
          float x = acc[am][nf][rr];
          float xp = __shfl_xor(x, 1);
          int s = row + rr;
          float2 cs = csf[(s << 6) | j];
          float y = odd ? (x * cs.x + xp * cs.y) : (x * cs.x - xp * cs.y);
          C[(long)s * N + col] = (bf16)y;
        }
      } else {
#pragma unroll
        for (int rr = 0; rr < 4; ++rr) {
          float v = acc[am][nf][rr];
          if constexpr (sizeof(OutT) == 4) C[(long)(row + rr) * N + col] = v;
          else                             C[(long)(row + rr) * N + col] = (bf16)v;
        }
      }
    }
  }
}

// ---------------- GQA causal flash attention, v10: 32x32 MFMA ----------------
// 2x FLOP per LDS byte vs 16x16 (attn was LDS-read-bound). 4 waves x 32 q-rows,
// KVBLK=64, swapped QK (lane owns q=lane&31, 32 S-vals in regs, 1 shfl reduce),
// P->PV zero-shuffle via kv bit-swap(3<->2) permutation baked into V staging.
#define AK_BAR() { asm volatile("s_waitcnt vmcnt(4)" ::: "memory");                      \
                   __builtin_amdgcn_sched_barrier(0);                                    \
                   asm volatile("s_waitcnt lgkmcnt(0)" ::: "memory");                    \
                   __builtin_amdgcn_s_barrier(); }

#define AK_ISSUEV(base, ra0, ra1, rb0, rb1) {                                            \
    long rv_ = (long)(base) + kva; if (rv_ > 2046) rv_ = 2046;                           \
    const bf16* vs_ = vbase + rv_ * QKV_N + dchunk * 16;                                 \
    ra0 = *reinterpret_cast<const bf16x8*>(vs_);                                         \
    rb0 = *reinterpret_cast<const bf16x8*>(vs_ + 8);                                     \
    ra1 = *reinterpret_cast<const bf16x8*>(vs_ + QKV_N);                                 \
    rb1 = *reinterpret_cast<const bf16x8*>(vs_ + QKV_N + 8); }

#define AK_WRITEV(ra0, ra1, rb0, rb1, vtb) {                                             \
    _Pragma("unroll") for (int e = 0; e < 8; ++e) {                                      \
      bf16x2 pk; pk[0] = ra0[e]; pk[1] = ra1[e];                                         \
      *reinterpret_cast<bf16x2*>(Vt[vtb] + (dchunk * 16 + e) * PADV + slot) = pk;        \
    }                                                                                    \
    _Pragma("unroll") for (int e = 0; e < 8; ++e) {                                      \
      bf16x2 pk; pk[0] = rb0[e]; pk[1] = rb1[e];                                         \
      *reinterpret_cast<bf16x2*>(Vt[vtb] + (dchunk * 16 + 8 + e) * PADV + slot) = pk;    \
    } }

#define AK_ISSUEK(base, buf) {                                                           \
    _Pragma("unroll") for (int i_ = 0; i_ < 4; ++i_) {                                   \
      int c_ = i_ * 256 + t;                                                             \
      int r_ = c_ >> 4, jl_ = c_ & 15, jg_ = jl_ ^ (r_ & 15);                            \
      long rk_ = (long)(base) + r_; if (rk_ > 2047) rk_ = 2047;                          \
      const bf16* src_ = kbase + rk_ * QKV_N + jg_ * 8;                                  \
      __builtin_amdgcn_global_load_lds((const __attribute__((address_space(1))) void*)src_,\
          (__attribute__((address_space(3))) void*)(Ks[buf] + c_ * 8), 16, 0, 0);        \
    } }

#define AK_STEP(stv, bufb) {                                                             \
    const int st_ = (stv);                                                               \
    const int kv0_ = st_ * 64;                                                           \
    if (kv0_ <= q0 + w * 32 + 31) {                                                      \
      f32x16 s0t, s1t;                                                                   \
      _Pragma("unroll") for (int e = 0; e < 16; ++e) { s0t[e] = 0.f; s1t[e] = 0.f; }     \
      __builtin_amdgcn_s_setprio(1);                                                     \
      _Pragma("unroll") for (int c0 = 0; c0 < 8; ++c0) {                                 \
        int swz_ = ((2 * c0 + hi) ^ (lane & 15)) << 3;                                   \
        bf16x8 k0 = *reinterpret_cast<const bf16x8*>(Ks[bufb] + ql * 128 + swz_);        \
        bf16x8 k1 = *reinterpret_cast<const bf16x8*>(Ks[bufb] + (32 + ql) * 128 + swz_); \
        s0t = __builtin_amdgcn_mfma_f32_32x32x16_bf16(k0, qf[c0], s0t, 0, 0, 0);         \
        s1t = __builtin_amdgcn_mfma_f32_32x32x16_bf16(k1, qf[c0], s1t, 0, 0, 0);         \
      }                                                                                  \
      __builtin_amdgcn_s_setprio(0);                                                     \
      const float SC = 0.12751742f;                                                      \
      float sl[32];                                                                      \
      _Pragma("unroll") for (int r = 0; r < 16; ++r) {                                   \
        int kvr_ = (r & 3) + 8 * (r >> 2) + 4 * hi;                                      \
        float v0 = s0t[r] * SC, v1 = s1t[r] * SC;                                        \
        if (st_ >= nst - 2) {                                                            \
          if (kv0_ + kvr_ > qg) v0 = -1e30f;                                             \
          if (kv0_ + 32 + kvr_ > qg) v1 = -1e30f;                                        \
        }                                                                                \
        sl[r] = v0; sl[16 + r] = v1;                                                     \
      }                                                                                  \
      float tm = sl[0];                                                                  \
      _Pragma("unroll") for (int e = 1; e < 32; ++e) tm = fmaxf(tm, sl[e]);              \
      tm = fmaxf(tm, __shfl_xor(tm, 32));                                                \
      if (__any(tm > mrow + 8.f)) {                                                      \
        float mnew = fmaxf(mrow, tm);                                                    \
        float alpha = exp2f(mrow - mnew);                                                \
        mrow = mnew; lrow *= alpha;                                                      \
        float ar[16];                                                                    \
        _Pragma("unroll") for (int r = 0; r < 16; ++r)                                   \
          ar[r] = __shfl(alpha, (r & 3) + 8 * (r >> 2) + 4 * hi);                        \
        _Pragma("unroll") for (int dt = 0; dt < 4; ++dt)                                 \
          _Pragma("unroll") for (int r = 0; r < 16; ++r) o[dt][r] *= ar[r];              \
      }                                                                                  \
      float pr[32]; float psum = 0.f;                                                    \
      _Pragma("unroll") for (int e = 0; e < 32; ++e) {                                   \
        pr[e] = exp2f(sl[e] - mrow); psum += pr[e];                                      \
      }                                                                                  \
      psum += __shfl_xor(psum, 32);                                                      \
      lrow += psum;                                                                      \
      bf16x8 pa[4];                                                                      \
      _Pragma("unroll") for (int pt = 0; pt < 4; ++pt)                                   \
        _Pragma("unroll") for (int j = 0; j < 8; ++j)                                    \
          pa[pt][j] = (bf16)pr[(pt >> 1) * 16 + j + 8 * (pt & 1)];                       \
      __builtin_amdgcn_s_setprio(1);                                                     \
      _Pragma("unroll") for (int dt = 0; dt < 4; ++dt)                                   \
        _Pragma("unroll") for (int pt = 0; pt < 4; ++pt) {                               \
          bf16x8 vf = *reinterpret_cast<const bf16x8*>(                                  \
              Vt[bufb] + (dt * 32 + ql) * PADV + pt * 16 + 8 * hi);                      \
          o[dt] = __builtin_amdgcn_mfma_f32_32x32x16_bf16(pa[pt], vf, o[dt], 0, 0, 0);   \
        }                                                                                \
      __builtin_amdgcn_s_setprio(0);                                                     \
    } }

__global__ __launch_bounds__(256, 2) void attn_kernel(const bf16* __restrict__ qkv,
                                                      bf16* __restrict__ out) {
  __shared__ __align__(16) bf16 Ks[2][64 * 128];
  __shared__ __align__(16) bf16 Vt[2][128 * PADV];

  const int bx = blockIdx.x;
  const int qt = (bx < 256) ? (15 - (bx >> 5)) : ((bx - 256) >> 5);  // balanced pairing
  const int h = bx & 31;                // head -> fixed XCD: KV L2 locality
  const int kvh = h >> 2;               // GROUPS = 4
  const int q0 = qt * 128;
  const int t = threadIdx.x, lane = t & 63, w = t >> 6;   // 4 waves x 32 q-rows
  const int ql = lane & 31, hi = lane >> 5;
  const int dchunk = t >> 5, kv2 = t & 31;                // V-staging: 2 kv rows x 16 d
  const int kva = kv2 * 2;
  const int slot = (kva & ~12) | ((kva & 8) >> 1) | ((kva & 4) << 1);  // kv bit-swap 3<->2
  const bf16* kbase = qkv + K_COL + kvh * HD;
  const bf16* vbase = qkv + V_COL + kvh * HD;

  const long qrow = q0 + w * 32 + ql;
  const int qg = q0 + w * 32 + ql;
  bf16x8 qf[8];                         // Q[q=ql][d = 16*c0 + 8*hi + 0..7]
#pragma unroll
  for (int c0 = 0; c0 < 8; ++c0)
    qf[c0] = *reinterpret_cast<const bf16x8*>(qkv + qrow * QKV_N + h * HD + c0 * 16 + hi * 8);

  f32x16 o[4];
#pragma unroll
  for (int dt = 0; dt < 4; ++dt)
#pragma unroll
    for (int e = 0; e < 16; ++e) o[dt][e] = 0.f;
  float mrow = -1e30f, lrow = 0.f;

  const int nst = 2 * qt + 2;
  bf16x8 va0, va1, va2, va3, vb0, vb1, vb2, vb3;

  // ---- prologue ----
  AK_ISSUEK(0, 0);
  AK_ISSUEV(0, va0, va1, va2, va3);
  AK_WRITEV(va0, va1, va2, va3, 0);     // waits va (drains K(0) too; one-time)
  AK_ISSUEV(64, vb0, vb1, vb2, vb3);
  asm volatile("s_waitcnt lgkmcnt(0)" ::: "memory");
  __builtin_amdgcn_s_barrier();

  for (int I = 0; I < (nst >> 1); ++I) {
    const int s0 = 2 * I;
    AK_ISSUEK((s0 + 1) * 64, 1);
    AK_ISSUEV((s0 + 2) * 64, va0, va1, va2, va3);
    AK_WRITEV(vb0, vb1, vb2, vb3, 1);
    AK_STEP(s0, 0);
    AK_BAR();
    AK_ISSUEK((s0 + 2) * 64, 0);
    AK_ISSUEV((s0 + 3) * 64, vb0, vb1, vb2, vb3);
    AK_WRITEV(va0, va1, va2, va3, 0);
    AK_STEP(s0 + 1, 1);
    AK_BAR();
  }

  // ---- epilogue: normalize + store ----
#pragma unroll
  for (int r = 0; r < 16; ++r) {
    int rowq = (r & 3) + 8 * (r >> 2) + 4 * hi;
    float iv = 1.0f / __shfl(lrow, rowq);
    long row = q0 + w * 32 + rowq;
#pragma unroll
    for (int dt = 0; dt < 4; ++dt)
      out[row * HID_DIM + h * HD + dt * 32 + ql] = (bf16)(o[dt][r] * iv);
  }
}

extern "C" void kernel_launch(void* const* d_in, const int* in_sizes, int n_in,
                              void* d_out, int out_size, void* d_ws, size_t ws_size,
                              hipStream_t stream) {
  const float* hs = (const float*)d_in[0];
  const float* Wq = (const float*)d_in[1];
  const float* Wk = (const float*)d_in[2];
  const float* Wv = (const float*)d_in[3];
  const float* Wo = (const float*)d_in[4];
  float* out = (float*)d_out;
  char* ws = (char*)d_ws;

  bf16*   hsb   = (bf16*)(ws);                    // 2048x4096 bf16
  bf16*   wqkvb = (bf16*)(ws + 16777216);         // 6144x4096 bf16
  bf16*   wob   = (bf16*)(ws + 67108864);         // 4096x4096 bf16
  bf16*   qkv   = (bf16*)(ws + 100663296);        // 2048x6144 bf16
  bf16*   attn  = (bf16*)(ws + 125829120);        // 2048x4096 bf16
  float2* csf   = (float2*)(ws + 142606336);      // 2048x64 float2 (cos,sin)

  cvt_all_kernel<<<49664, 256, 0, stream>>>(hs, Wq, Wk, Wv, Wo, hsb, wqkvb, wob, csf);
  gemm4p_kernel<3, true, bf16><<<dim3(32, 8), 512, 0, stream>>>(hsb, wqkvb, qkv, 2048, 6144, 4096, csf);
  attn_kernel<<<512, 256, 0, stream>>>(qkv, attn);
  gemm4p_kernel<2, false, float><<<dim3(32, 8), 512, 0, stream>>>(attn, wob, out, 2048, 4096, 4096, nullptr);
}

// Round 14
// 296.642 us; speedup vs baseline: 1.0556x; 1.0556x over previous
//
#include <hip/hip_runtime.h>

typedef __bf16 bf16;
typedef __bf16 bf16x2 __attribute__((ext_vector_type(2)));
typedef __bf16 bf16x4 __attribute__((ext_vector_type(4)));
typedef __bf16 bf16x8 __attribute__((ext_vector_type(8)));
typedef float f32x4 __attribute__((ext_vector_type(4)));

#define S_LEN 2048
#define HID_DIM 4096
#define NH 32
#define NKV 8
#define HD 128
#define QKV_N 6144   // 4096 Q + 1024 K + 1024 V
#define K_COL 4096
#define V_COL 5120
#define PADV 76

// ------- fused fp32->bf16 conversion + RoPE tables (float2 cos,sin) -------
// Wq/Wk rows PERMUTED so RoPE pairs (d,d+64) land in adjacent qkv columns.
__global__ void cvt_all_kernel(const float* __restrict__ hs, const float* __restrict__ wq,
                               const float* __restrict__ wk, const float* __restrict__ wv,
                               const float* __restrict__ wo, bf16* __restrict__ hsb,
                               bf16* __restrict__ wqkvb, bf16* __restrict__ wob,
                               float2* __restrict__ csf) {
  long i = (long)blockIdx.x * blockDim.x + threadIdx.x;
  if (i >= 12582912) {                   // RoPE tables: 2048*64 entries
    int j = (int)(i - 12582912);
    int s = j >> 6, d = j & 63;
    float inv = expf(-0.14391156831212787f * (float)d);   // 10000^(-d/64)
    float ang = (float)s * inv;
    csf[j] = make_float2(cosf(ang), sinf(ang));
    return;
  }
  const float* src; bf16* dst; long off; bool perm = false;
  if (i < 2097152)      { src = hs; dst = hsb;                          off = i; }
  else if (i < 6291456) { src = wq; dst = wqkvb;                        off = i - 2097152; perm = true; }
  else if (i < 7340032) { src = wk; dst = wqkvb + (long)4096 * 4096;    off = i - 6291456; perm = true; }
  else if (i < 8388608) { src = wv; dst = wqkvb + (long)5120 * 4096;    off = i - 7340032; }
  else                  { src = wo; dst = wob;                          off = i - 8388608; }
  float4 v = reinterpret_cast<const float4*>(src)[off];
  bf16x4 o;
  o[0] = (bf16)v.x; o[1] = (bf16)v.y; o[2] = (bf16)v.z; o[3] = (bf16)v.w;
  long doff = off;
  if (perm) {
    long r = off >> 10, c4 = off & 1023;
    long d = r & 127;
    long pd = ((d & 63) << 1) | (d >> 6);
    doff = (((r & ~127L) | pd) << 10) | c4;
  }
  reinterpret_cast<bf16x4*>(dst)[doff] = o;
}

// ---- 4-phase GEMM: BM=256, BN=NB*64, BK=64 (R8 schedule) + optional fused RoPE ----
#define STG8(buf, mat, kt, unit) {                                                       \
    const bf16* sp_ = (mat) ? Bp : Ap;                                                   \
    int row0_ = ((mat) ? n0 : m0) + (unit) * 64;                                         \
    int lb_ = (buf) * LBUF + (mat) * 16384 + (unit) * 4096;                              \
    int r_ = t >> 3, jl_ = t & 7, jg_ = jl_ ^ (r_ & 7);                                  \
    const bf16* src_ = sp_ + (long)(row0_ + r_) * K + (kt) * 64 + jg_ * 8;               \
    __builtin_amdgcn_global_load_lds((const __attribute__((address_space(1))) void*)src_,\
        (__attribute__((address_space(3))) void*)(L + lb_ + t * 8), 16, 0, 0); }

#define DSA2(buf, mh) {                                                                  \
    _Pragma("unroll") for (int ks_ = 0; ks_ < 2; ++ks_)                                  \
      _Pragma("unroll") for (int mf_ = 0; mf_ < 4; ++mf_) {                              \
        int R_ = wr * 128 + (mh) * 64 + mf_ * 16 + lm;                                   \
        aF[ks_][mf_] = *reinterpret_cast<const bf16x8*>(                                 \
            L + (buf) * LBUF + R_ * 64 + (((ks_ * 4 + lg) ^ (R_ & 7)) << 3));            \
      } }

#define DSBALL(buf) {                                                                    \
    _Pragma("unroll") for (int ks_ = 0; ks_ < 2; ++ks_)                                  \
      _Pragma("unroll") for (int nf_ = 0; nf_ < NB; ++nf_) {                             \
        int R_ = wc * (NB * 16) + nf_ * 16 + lm;                                         \
        bF[ks_][nf_] = *reinterpret_cast<const bf16x8*>(                                 \
            L + (buf) * LBUF + 16384 + R_ * 64 + (((ks_ * 4 + lg) ^ (R_ & 7)) << 3));    \
      } }

#define MM2(mh) {                                                                        \
    __builtin_amdgcn_s_setprio(1);                                                       \
    _Pragma("unroll") for (int mf_ = 0; mf_ < 4; ++mf_)                                  \
      _Pragma("unroll") for (int nf_ = 0; nf_ < NB; ++nf_)                               \
        _Pragma("unroll") for (int ks_ = 0; ks_ < 2; ++ks_)                              \
          acc[(mh) * 4 + mf_][nf_] = __builtin_amdgcn_mfma_f32_16x16x32_bf16(            \
              aF[ks_][mf_], bF[ks_][nf_], acc[(mh) * 4 + mf_][nf_], 0, 0, 0);            \
    __builtin_amdgcn_s_setprio(0); }

#define BAR() __builtin_amdgcn_s_barrier()
#define WVM(n) asm volatile("s_waitcnt vmcnt(%0)" :: "i"(n) : "memory")

template<int NB, bool ROPE, typename OutT>
__global__ __launch_bounds__(512, 1) void gemm4p_kernel(
    const bf16* __restrict__ Ap, const bf16* __restrict__ Bp, OutT* __restrict__ C,
    int M, int N, int K, const float2* __restrict__ csf) {
  constexpr int LBUF = 16384 + NB * 4096;
  __shared__ __align__(16) bf16 L[2 * LBUF];

  int nwg = gridDim.x * gridDim.y;
  int bid = blockIdx.y * gridDim.x + blockIdx.x;
  int cpx = nwg >> 3;
  int swz = (bid & 7) * cpx + (bid >> 3);
  int bxs = swz % gridDim.x, bys = swz / gridDim.x;
  const int n0 = bxs * (NB * 64), m0 = bys * 256;

  const int t = threadIdx.x;
  const int lane = t & 63, w = t >> 6;
  const int wr = w >> 2, wc = w & 3;
  const int lg = lane >> 4, lm = lane & 15;
  const int NT = K >> 6;

  f32x4 acc[8][NB] = {};
  bf16x8 aF[2][4], bF[2][NB];

  STG8(0, 0, 0, 0); STG8(0, 0, 0, 1); STG8(0, 0, 0, 2); STG8(0, 0, 0, 3);
  STG8(0, 1, 0, 0); if (NB > 1) STG8(0, 1, 0, 1); if (NB > 2) STG8(0, 1, 0, 2);
  STG8(1, 1, 1, 0); if (NB > 1) STG8(1, 1, 1, 1); if (NB > 2) STG8(1, 1, 1, 2);
  WVM(NB);
  BAR();

  for (int I = 0; I < (NT >> 1); ++I) {
    const int tt = 2 * I;
    const bool pf = (I < (NT >> 1) - 1);
    DSA2(0, 0); DSBALL(0);
    STG8(1, 0, tt + 1, 0); STG8(1, 0, tt + 1, 1);
    STG8(1, 0, tt + 1, 2); STG8(1, 0, tt + 1, 3);
    BAR(); MM2(0); BAR();
    DSA2(0, 1);
    if (pf) { STG8(0, 1, tt + 2, 0); if (NB > 1) STG8(0, 1, tt + 2, 1);
              if (NB > 2) STG8(0, 1, tt + 2, 2); }
    BAR(); MM2(1);
    if (pf) WVM(NB); else WVM(0);
    BAR();
    DSA2(1, 0); DSBALL(1);
    if (pf) { STG8(0, 0, tt + 2, 0); STG8(0, 0, tt + 2, 1);
              STG8(0, 0, tt + 2, 2); STG8(0, 0, tt + 2, 3); }
    BAR(); MM2(0); BAR();
    DSA2(1, 1);
    if (pf) { STG8(1, 1, tt + 3, 0); if (NB > 1) STG8(1, 1, tt + 3, 1);
              if (NB > 2) STG8(1, 1, tt + 3, 2); }
    BAR(); MM2(1);
    if (pf) WVM(NB); else WVM(0);
    BAR();
  }

  // ---- epilogue (optionally fused RoPE for Q/K columns) ----
#pragma unroll
  for (int am = 0; am < 8; ++am) {
    int row = m0 + wr * 128 + am * 16 + lg * 4;
#pragma unroll
    for (int nf = 0; nf < NB; ++nf) {
      int col = n0 + wc * (NB * 16) + nf * 16 + lm;
      if (ROPE && col < V_COL) {
        int j = (col & 127) >> 1;
        bool odd = col & 1;
#pragma unroll
        for (int rr = 0; rr < 4; ++rr) {
          float x = acc[am][nf][rr];
          float xp = __shfl_xor(x, 1);
          int s = row + rr;
          float2 cs = csf[(s << 6) | j];
          float y = odd ? (x * cs.x + xp * cs.y) : (x * cs.x - xp * cs.y);
          C[(long)s * N + col] = (bf16)y;
        }
      } else {
#pragma unroll
        for (int rr = 0; rr < 4; ++rr) {
          float v = acc[am][nf][rr];
          if constexpr (sizeof(OutT) == 4) C[(long)(row + rr) * N + col] = v;
          else                             C[(long)(row + rr) * N + col] = (bf16)v;
        }
      }
    }
  }
}

// ---------------- GQA causal flash attention, v9 (R12 exact, known-best) ----------------
// 8 waves x 16 q-rows, KVBLK=64, swapped QK (lane owns q-row), zero-shuffle P->PV
// via kv-window permutation baked into V staging; Ks[2]+Vt[2]; one barrier/step
// with counted vmcnt(2); balanced CU pairing.
#define AK_BAR() { asm volatile("s_waitcnt vmcnt(2)" ::: "memory");                      \
                   __builtin_amdgcn_sched_barrier(0);                                    \
                   asm volatile("s_waitcnt lgkmcnt(0)" ::: "memory");                    \
                   __builtin_amdgcn_s_barrier(); }

#define AK_WRITEV(r0, r1, vtb) {                                                         \
    _Pragma("unroll") for (int e = 0; e < 8; ++e) {                                      \
      bf16x2 pk; pk[0] = r0[e]; pk[1] = r1[e];                                           \
      *reinterpret_cast<bf16x2*>(Vt[vtb] + (dchunk * 8 + e) * PADV + slot) = pk;         \
    } }

#define AK_ISSUEV(base, r0, r1) {                                                        \
    long rv_ = (long)(base) + kva; if (rv_ > 2046) rv_ = 2046;                           \
    const bf16* vs_ = vbase + rv_ * QKV_N + dchunk * 8;                                  \
    r0 = *reinterpret_cast<const bf16x8*>(vs_);                                          \
    r1 = *reinterpret_cast<const bf16x8*>(vs_ + QKV_N); }

#define AK_ISSUEK(base, buf) {                                                           \
    _Pragma("unroll") for (int i_ = 0; i_ < 2; ++i_) {                                   \
      int c_ = i_ * 512 + t;                                                             \
      int r_ = c_ >> 4, jl_ = c_ & 15, jg_ = jl_ ^ (r_ & 15);                            \
      long rk_ = (long)(base) + r_; if (rk_ > 2047) rk_ = 2047;                          \
      const bf16* src_ = kbase + rk_ * QKV_N + jg_ * 8;                                  \
      __builtin_amdgcn_global_load_lds((const __attribute__((address_space(1))) void*)src_,\
          (__attribute__((address_space(3))) void*)(Ks[buf] + c_ * 8), 16, 0, 0);        \
    } }

#define AK_STEP(stv, bufb) {                                                             \
    const int st_ = (stv);                                                               \
    const int kv0_ = st_ * 64;                                                           \
    if (kv0_ <= q0 + w * 16 + 15) {                                                      \
      f32x4 s[4];                                                                        \
      _Pragma("unroll") for (int cb = 0; cb < 4; ++cb) s[cb] = f32x4{0.f,0.f,0.f,0.f};   \
      __builtin_amdgcn_s_setprio(1);                                                     \
      _Pragma("unroll") for (int ks = 0; ks < 4; ++ks)                                   \
        _Pragma("unroll") for (int cb = 0; cb < 4; ++cb) {                               \
          bf16x8 kf = *reinterpret_cast<const bf16x8*>(                                  \
              Ks[bufb] + (cb * 16 + lm) * 128 + (((ks * 4 + lg) ^ lm) << 3));            \
          s[cb] = __builtin_amdgcn_mfma_f32_16x16x32_bf16(kf, qf[ks], s[cb], 0, 0, 0);   \
        }                                                                                \
      __builtin_amdgcn_s_setprio(0);                                                     \
      const float SC = 0.12751742f;                                                      \
      float sl[4][4];                                                                    \
      _Pragma("unroll") for (int cb = 0; cb < 4; ++cb)                                   \
        _Pragma("unroll") for (int r = 0; r < 4; ++r) {                                  \
          float v = s[cb][r] * SC;                                                       \
          if (st_ >= nst - 2 && (kv0_ + cb * 16 + lg * 4 + r) > qg) v = -1e30f;          \
          sl[cb][r] = v;                                                                 \
        }                                                                                \
      float tm = sl[0][0];                                                               \
      _Pragma("unroll") for (int cb = 0; cb < 4; ++cb)                                   \
        _Pragma("unroll") for (int r = 0; r < 4; ++r) tm = fmaxf(tm, sl[cb][r]);         \
      tm = fmaxf(tm, __shfl_xor(tm, 16));                                                \
      tm = fmaxf(tm, __shfl_xor(tm, 32));                                                \
      if (__any(tm > mrow + 8.f)) {                                                      \
        float mnew = fmaxf(mrow, tm);                                                    \
        float alpha = exp2f(mrow - mnew);                                                \
        mrow = mnew; lrow *= alpha;                                                      \
        float ar[4];                                                                     \
        _Pragma("unroll") for (int r = 0; r < 4; ++r)                                    \
          ar[r] = __shfl(alpha, (lane & 48) | (lg * 4 + r));                             \
        _Pragma("unroll") for (int i = 0; i < 8; ++i)                                    \
          _Pragma("unroll") for (int r = 0; r < 4; ++r) o[i][r] *= ar[r];                \
      }                                                                                  \
      float p[4][4]; float psum = 0.f;                                                   \
      _Pragma("unroll") for (int cb = 0; cb < 4; ++cb)                                   \
        _Pragma("unroll") for (int r = 0; r < 4; ++r) {                                  \
          p[cb][r] = exp2f(sl[cb][r] - mrow); psum += p[cb][r];                          \
        }                                                                                \
      psum += __shfl_xor(psum, 16);                                                      \
      psum += __shfl_xor(psum, 32);                                                      \
      lrow += psum;                                                                      \
      bf16x8 pa0, pa1;                                                                   \
      _Pragma("unroll") for (int r = 0; r < 4; ++r) {                                    \
        pa0[r] = (bf16)p[0][r]; pa0[4 + r] = (bf16)p[1][r];                              \
        pa1[r] = (bf16)p[2][r]; pa1[4 + r] = (bf16)p[3][r];                              \
      }                                                                                  \
      __builtin_amdgcn_s_setprio(1);                                                     \
      _Pragma("unroll") for (int db = 0; db < 8; ++db) {                                 \
        bf16x8 vf0 = *reinterpret_cast<const bf16x8*>(Vt[bufb] + (db*16+lm)*PADV + lg*8);\
        bf16x8 vf1 = *reinterpret_cast<const bf16x8*>(Vt[bufb] + (db*16+lm)*PADV + 32 + lg*8);\
        o[db] = __builtin_amdgcn_mfma_f32_16x16x32_bf16(pa0, vf0, o[db], 0, 0, 0);       \
        o[db] = __builtin_amdgcn_mfma_f32_16x16x32_bf16(pa1, vf1, o[db], 0, 0, 0);       \
      }                                                                                  \
      __builtin_amdgcn_s_setprio(0);                                                     \
    } }

__global__ __launch_bounds__(512, 4) void attn_kernel(const bf16* __restrict__ qkv,
                                                      bf16* __restrict__ out) {
  __shared__ __align__(16) bf16 Ks[2][64 * 128];
  __shared__ __align__(16) bf16 Vt[2][128 * PADV];

  const int bx = blockIdx.x;
  // balanced CU pairing: block c (c<256) gets qt=15-(c>>5), block c+256 gets qt=(c>>5)
  const int qt = (bx < 256) ? (15 - (bx >> 5)) : ((bx - 256) >> 5);
  const int h = bx & 31;                // head -> fixed XCD: KV L2 locality
  const int kvh = h >> 2;               // GROUPS = 4
  const int q0 = qt * 128;
  const int t = threadIdx.x, lane = t & 63, w = t >> 6;   // 8 waves
  const int lg = lane >> 4, lm = lane & 15;
  const int dchunk = t >> 5, kv2 = t & 31;
  const int kva = kv2 * 2;
  const int k5 = kva & 31;
  const int slot = ((kva >> 5) << 5) | (((k5 >> 2) & 3) << 3) | ((k5 >> 4) << 2) | (k5 & 3);
  const bf16* kbase = qkv + K_COL + kvh * HD;
  const bf16* vbase = qkv + V_COL + kvh * HD;

  const long qrow = q0 + w * 16 + lm;
  const int qg = q0 + w * 16 + lm;
  bf16x8 qf[4];
#pragma unroll
  for (int ks = 0; ks < 4; ++ks)
    qf[ks] = *reinterpret_cast<const bf16x8*>(qkv + qrow * QKV_N + h * HD + ks * 32 + lg * 8);

  f32x4 o[8];
#pragma unroll
  for (int i = 0; i < 8; ++i) o[i] = f32x4{0.f, 0.f, 0.f, 0.f};
  float mrow = -1e30f, lrow = 0.f;

  const int nst = 2 * qt + 2;
  bf16x8 va0, va1, vb0, vb1;

  // ---- prologue ----
  AK_ISSUEK(0, 0);
  AK_ISSUEV(0, va0, va1);
  AK_WRITEV(va0, va1, 0);
  AK_ISSUEV(64, vb0, vb1);
  asm volatile("s_waitcnt lgkmcnt(0)" ::: "memory");
  __builtin_amdgcn_s_barrier();

  for (int I = 0; I < (nst >> 1); ++I) {
    const int s0 = 2 * I;
    AK_ISSUEK((s0 + 1) * 64, 1);
    AK_ISSUEV((s0 + 2) * 64, va0, va1);
    AK_WRITEV(vb0, vb1, 1);
    AK_STEP(s0, 0);
    AK_BAR();
    AK_ISSUEK((s0 + 2) * 64, 0);
    AK_ISSUEV((s0 + 3) * 64, vb0, vb1);
    AK_WRITEV(va0, va1, 0);
    AK_STEP(s0 + 1, 1);
    AK_BAR();
  }

  // ---- epilogue ----
  float invr[4];
#pragma unroll
  for (int r = 0; r < 4; ++r)
    invr[r] = 1.0f / __shfl(lrow, (lane & 48) | (lg * 4 + r));
#pragma unroll
  for (int r = 0; r < 4; ++r) {
    long row = q0 + w * 16 + lg * 4 + r;
#pragma unroll
    for (int db = 0; db < 8; ++db)
      out[row * HID_DIM + h * HD + db * 16 + lm] = (bf16)(o[db][r] * invr[r]);
  }
}

extern "C" void kernel_launch(void* const* d_in, const int* in_sizes, int n_in,
                              void* d_out, int out_size, void* d_ws, size_t ws_size,
                              hipStream_t stream) {
  const float* hs = (const float*)d_in[0];
  const float* Wq = (const float*)d_in[1];
  const float* Wk = (const float*)d_in[2];
  const float* Wv = (const float*)d_in[3];
  const float* Wo = (const float*)d_in[4];
  float* out = (float*)d_out;
  char* ws = (char*)d_ws;

  bf16*   hsb   = (bf16*)(ws);                    // 2048x4096 bf16
  bf16*   wqkvb = (bf16*)(ws + 16777216);         // 6144x4096 bf16
  bf16*   wob   = (bf16*)(ws + 67108864);         // 4096x4096 bf16
  bf16*   qkv   = (bf16*)(ws + 100663296);        // 2048x6144 bf16
  bf16*   attn  = (bf16*)(ws + 125829120);        // 2048x4096 bf16
  float2* csf   = (float2*)(ws + 142606336);      // 2048x64 float2 (cos,sin)

  cvt_all_kernel<<<49664, 256, 0, stream>>>(hs, Wq, Wk, Wv, Wo, hsb, wqkvb, wob, csf);
  gemm4p_kernel<3, true, bf16><<<dim3(32, 8), 512, 0, stream>>>(hsb, wqkvb, qkv, 2048, 6144, 4096, csf);
  attn_kernel<<<512, 512, 0, stream>>>(qkv, attn);
  gemm4p_kernel<2, false, float><<<dim3(32, 8), 512, 0, stream>>>(attn, wob, out, 2048, 4096, 4096, nullptr);
}

// Round 15
// 291.972 us; speedup vs baseline: 1.0724x; 1.0160x over previous
//
#include <hip/hip_runtime.h>

typedef __bf16 bf16;
typedef __bf16 bf16x2 __attribute__((ext_vector_type(2)));
typedef __bf16 bf16x4 __attribute__((ext_vector_type(4)));
typedef __bf16 bf16x8 __attribute__((ext_vector_type(8)));
typedef float f32x4 __attribute__((ext_vector_type(4)));

#define S_LEN 2048
#define HID_DIM 4096
#define NH 32
#define NKV 8
#define HD 128
#define QKV_N 6144   // 4096 Q + 1024 K + 1024 V
#define K_COL 4096
#define V_COL 5120
#define PADV 76

// ------- fused fp32->bf16 conversion (hs, Wq, Wk, Wv) + RoPE tables -------
// Wo conversion is deferred into attn_kernel's tail (rides attn's idle HBM BW).
// Wq/Wk rows PERMUTED so RoPE pairs (d,d+64) land in adjacent qkv columns.
__global__ void cvt_all_kernel(const float* __restrict__ hs, const float* __restrict__ wq,
                               const float* __restrict__ wk, const float* __restrict__ wv,
                               bf16* __restrict__ hsb, bf16* __restrict__ wqkvb,
                               float2* __restrict__ csf) {
  long i = (long)blockIdx.x * blockDim.x + threadIdx.x;
  if (i >= 8388608) {                    // RoPE tables: 2048*64 entries
    int j = (int)(i - 8388608);
    int s = j >> 6, d = j & 63;
    float inv = expf(-0.14391156831212787f * (float)d);   // 10000^(-d/64)
    float ang = (float)s * inv;
    csf[j] = make_float2(cosf(ang), sinf(ang));
    return;
  }
  const float* src; bf16* dst; long off; bool perm = false;
  if (i < 2097152)      { src = hs; dst = hsb;                          off = i; }
  else if (i < 6291456) { src = wq; dst = wqkvb;                        off = i - 2097152; perm = true; }
  else if (i < 7340032) { src = wk; dst = wqkvb + (long)4096 * 4096;    off = i - 6291456; perm = true; }
  else                  { src = wv; dst = wqkvb + (long)5120 * 4096;    off = i - 7340032; }
  float4 v = reinterpret_cast<const float4*>(src)[off];
  bf16x4 o;
  o[0] = (bf16)v.x; o[1] = (bf16)v.y; o[2] = (bf16)v.z; o[3] = (bf16)v.w;
  long doff = off;
  if (perm) {
    long r = off >> 10, c4 = off & 1023;
    long d = r & 127;
    long pd = ((d & 63) << 1) | (d >> 6);
    doff = (((r & ~127L) | pd) << 10) | c4;
  }
  reinterpret_cast<bf16x4*>(dst)[doff] = o;
}

// ---- 4-phase GEMM: BM=256, BN=NB*64, BK=64 (R8 schedule) + optional fused RoPE ----
#define STG8(buf, mat, kt, unit) {                                                       \
    const bf16* sp_ = (mat) ? Bp : Ap;                                                   \
    int row0_ = ((mat) ? n0 : m0) + (unit) * 64;                                         \
    int lb_ = (buf) * LBUF + (mat) * 16384 + (unit) * 4096;                              \
    int r_ = t >> 3, jl_ = t & 7, jg_ = jl_ ^ (r_ & 7);                                  \
    const bf16* src_ = sp_ + (long)(row0_ + r_) * K + (kt) * 64 + jg_ * 8;               \
    __builtin_amdgcn_global_load_lds((const __attribute__((address_space(1))) void*)src_,\
        (__attribute__((address_space(3))) void*)(L + lb_ + t * 8), 16, 0, 0); }

#define DSA2(buf, mh) {                                                                  \
    _Pragma("unroll") for (int ks_ = 0; ks_ < 2; ++ks_)                                  \
      _Pragma("unroll") for (int mf_ = 0; mf_ < 4; ++mf_) {                              \
        int R_ = wr * 128 + (mh) * 64 + mf_ * 16 + lm;                                   \
        aF[ks_][mf_] = *reinterpret_cast<const bf16x8*>(                                 \
            L + (buf) * LBUF + R_ * 64 + (((ks_ * 4 + lg) ^ (R_ & 7)) << 3));            \
      } }

#define DSBALL(buf) {                                                                    \
    _Pragma("unroll") for (int ks_ = 0; ks_ < 2; ++ks_)                                  \
      _Pragma("unroll") for (int nf_ = 0; nf_ < NB; ++nf_) {                             \
        int R_ = wc * (NB * 16) + nf_ * 16 + lm;                                         \
        bF[ks_][nf_] = *reinterpret_cast<const bf16x8*>(                                 \
            L + (buf) * LBUF + 16384 + R_ * 64 + (((ks_ * 4 + lg) ^ (R_ & 7)) << 3));    \
      } }

#define MM2(mh) {                                                                        \
    __builtin_amdgcn_s_setprio(1);                                                       \
    _Pragma("unroll") for (int mf_ = 0; mf_ < 4; ++mf_)                                  \
      _Pragma("unroll") for (int nf_ = 0; nf_ < NB; ++nf_)                               \
        _Pragma("unroll") for (int ks_ = 0; ks_ < 2; ++ks_)                              \
          acc[(mh) * 4 + mf_][nf_] = __builtin_amdgcn_mfma_f32_16x16x32_bf16(            \
              aF[ks_][mf_], bF[ks_][nf_], acc[(mh) * 4 + mf_][nf_], 0, 0, 0);            \
    __builtin_amdgcn_s_setprio(0); }

#define BAR() __builtin_amdgcn_s_barrier()
#define WVM(n) asm volatile("s_waitcnt vmcnt(%0)" :: "i"(n) : "memory")

template<int NB, bool ROPE, typename OutT>
__global__ __launch_bounds__(512, 1) void gemm4p_kernel(
    const bf16* __restrict__ Ap, const bf16* __restrict__ Bp, OutT* __restrict__ C,
    int M, int N, int K, const float2* __restrict__ csf) {
  constexpr int LBUF = 16384 + NB * 4096;
  __shared__ __align__(16) bf16 L[2 * LBUF];

  int nwg = gridDim.x * gridDim.y;
  int bid = blockIdx.y * gridDim.x + blockIdx.x;
  int cpx = nwg >> 3;
  int swz = (bid & 7) * cpx + (bid >> 3);
  int bxs = swz % gridDim.x, bys = swz / gridDim.x;
  const int n0 = bxs * (NB * 64), m0 = bys * 256;

  const int t = threadIdx.x;
  const int lane = t & 63, w = t >> 6;
  const int wr = w >> 2, wc = w & 3;
  const int lg = lane >> 4, lm = lane & 15;
  const int NT = K >> 6;

  f32x4 acc[8][NB] = {};
  bf16x8 aF[2][4], bF[2][NB];

  STG8(0, 0, 0, 0); STG8(0, 0, 0, 1); STG8(0, 0, 0, 2); STG8(0, 0, 0, 3);
  STG8(0, 1, 0, 0); if (NB > 1) STG8(0, 1, 0, 1); if (NB > 2) STG8(0, 1, 0, 2);
  STG8(1, 1, 1, 0); if (NB > 1) STG8(1, 1, 1, 1); if (NB > 2) STG8(1, 1, 1, 2);
  WVM(NB);
  BAR();

  for (int I = 0; I < (NT >> 1); ++I) {
    const int tt = 2 * I;
    const bool pf = (I < (NT >> 1) - 1);
    DSA2(0, 0); DSBALL(0);
    STG8(1, 0, tt + 1, 0); STG8(1, 0, tt + 1, 1);
    STG8(1, 0, tt + 1, 2); STG8(1, 0, tt + 1, 3);
    BAR(); MM2(0); BAR();
    DSA2(0, 1);
    if (pf) { STG8(0, 1, tt + 2, 0); if (NB > 1) STG8(0, 1, tt + 2, 1);
              if (NB > 2) STG8(0, 1, tt + 2, 2); }
    BAR(); MM2(1);
    if (pf) WVM(NB); else WVM(0);
    BAR();
    DSA2(1, 0); DSBALL(1);
    if (pf) { STG8(0, 0, tt + 2, 0); STG8(0, 0, tt + 2, 1);
              STG8(0, 0, tt + 2, 2); STG8(0, 0, tt + 2, 3); }
    BAR(); MM2(0); BAR();
    DSA2(1, 1);
    if (pf) { STG8(1, 1, tt + 3, 0); if (NB > 1) STG8(1, 1, tt + 3, 1);
              if (NB > 2) STG8(1, 1, tt + 3, 2); }
    BAR(); MM2(1);
    if (pf) WVM(NB); else WVM(0);
    BAR();
  }

  // ---- epilogue (optionally fused RoPE for Q/K columns) ----
#pragma unroll
  for (int am = 0; am < 8; ++am) {
    int row = m0 + wr * 128 + am * 16 + lg * 4;
#pragma unroll
    for (int nf = 0; nf < NB; ++nf) {
      int col = n0 + wc * (NB * 16) + nf * 16 + lm;
      if (ROPE && col < V_COL) {
        int j = (col & 127) >> 1;
        bool odd = col & 1;
#pragma unroll
        for (int rr = 0; rr < 4; ++rr) {
          float x = acc[am][nf][rr];
          float xp = __shfl_xor(x, 1);
          int s = row + rr;
          float2 cs = csf[(s << 6) | j];
          float y = odd ? (x * cs.x + xp * cs.y) : (x * cs.x - xp * cs.y);
          C[(long)s * N + col] = (bf16)y;
        }
      } else {
#pragma unroll
        for (int rr = 0; rr < 4; ++rr) {
          float v = acc[am][nf][rr];
          if constexpr (sizeof(OutT) == 4) C[(long)(row + rr) * N + col] = v;
          else                             C[(long)(row + rr) * N + col] = (bf16)v;
        }
      }
    }
  }
}

// ---------------- GQA causal flash attention, v9 + Wo-conversion tail ----------------
// 8 waves x 16 q-rows, KVBLK=64, swapped QK (lane owns q-row), zero-shuffle P->PV
// via kv-window permutation baked into V staging; Ks[2]+Vt[2]; one barrier/step
// with counted vmcnt(2); balanced CU pairing. Tail converts Wo fp32->bf16 in the
// load-imbalance shadow (attn uses ~1/6 of HBM BW; Wo isn't needed until out-proj).
#define AK_BAR() { asm volatile("s_waitcnt vmcnt(2)" ::: "memory");                      \
                   __builtin_amdgcn_sched_barrier(0);                                    \
                   asm volatile("s_waitcnt lgkmcnt(0)" ::: "memory");                    \
                   __builtin_amdgcn_s_barrier(); }

#define AK_WRITEV(r0, r1, vtb) {                                                         \
    _Pragma("unroll") for (int e = 0; e < 8; ++e) {                                      \
      bf16x2 pk; pk[0] = r0[e]; pk[1] = r1[e];                                           \
      *reinterpret_cast<bf16x2*>(Vt[vtb] + (dchunk * 8 + e) * PADV + slot) = pk;         \
    } }

#define AK_ISSUEV(base, r0, r1) {                                                        \
    long rv_ = (long)(base) + kva; if (rv_ > 2046) rv_ = 2046;                           \
    const bf16* vs_ = vbase + rv_ * QKV_N + dchunk * 8;                                  \
    r0 = *reinterpret_cast<const bf16x8*>(vs_);                                          \
    r1 = *reinterpret_cast<const bf16x8*>(vs_ + QKV_N); }

#define AK_ISSUEK(base, buf) {                                                           \
    _Pragma("unroll") for (int i_ = 0; i_ < 2; ++i_) {                                   \
      int c_ = i_ * 512 + t;                                                             \
      int r_ = c_ >> 4, jl_ = c_ & 15, jg_ = jl_ ^ (r_ & 15);                            \
      long rk_ = (long)(base) + r_; if (rk_ > 2047) rk_ = 2047;                          \
      const bf16* src_ = kbase + rk_ * QKV_N + jg_ * 8;                                  \
      __builtin_amdgcn_global_load_lds((const __attribute__((address_space(1))) void*)src_,\
          (__attribute__((address_space(3))) void*)(Ks[buf] + c_ * 8), 16, 0, 0);        \
    } }

#define AK_STEP(stv, bufb) {                                                             \
    const int st_ = (stv);                                                               \
    const int kv0_ = st_ * 64;                                                           \
    if (kv0_ <= q0 + w * 16 + 15) {                                                      \
      f32x4 s[4];                                                                        \
      _Pragma("unroll") for (int cb = 0; cb < 4; ++cb) s[cb] = f32x4{0.f,0.f,0.f,0.f};   \
      __builtin_amdgcn_s_setprio(1);                                                     \
      _Pragma("unroll") for (int ks = 0; ks < 4; ++ks)                                   \
        _Pragma("unroll") for (int cb = 0; cb < 4; ++cb) {                               \
          bf16x8 kf = *reinterpret_cast<const bf16x8*>(                                  \
              Ks[bufb] + (cb * 16 + lm) * 128 + (((ks * 4 + lg) ^ lm) << 3));            \
          s[cb] = __builtin_amdgcn_mfma_f32_16x16x32_bf16(kf, qf[ks], s[cb], 0, 0, 0);   \
        }                                                                                \
      __builtin_amdgcn_s_setprio(0);                                                     \
      const float SC = 0.12751742f;                                                      \
      float sl[4][4];                                                                    \
      _Pragma("unroll") for (int cb = 0; cb < 4; ++cb)                                   \
        _Pragma("unroll") for (int r = 0; r < 4; ++r) {                                  \
          float v = s[cb][r] * SC;                                                       \
          if (st_ >= nst - 2 && (kv0_ + cb * 16 + lg * 4 + r) > qg) v = -1e30f;          \
          sl[cb][r] = v;                                                                 \
        }                                                                                \
      float tm = sl[0][0];                                                               \
      _Pragma("unroll") for (int cb = 0; cb < 4; ++cb)                                   \
        _Pragma("unroll") for (int r = 0; r < 4; ++r) tm = fmaxf(tm, sl[cb][r]);         \
      tm = fmaxf(tm, __shfl_xor(tm, 16));                                                \
      tm = fmaxf(tm, __shfl_xor(tm, 32));                                                \
      if (__any(tm > mrow + 8.f)) {                                                      \
        float mnew = fmaxf(mrow, tm);                                                    \
        float alpha = exp2f(mrow - mnew);                                                \
        mrow = mnew; lrow *= alpha;                                                      \
        float ar[4];                                                                     \
        _Pragma("unroll") for (int r = 0; r < 4; ++r)                                    \
          ar[r] = __shfl(alpha, (lane & 48) | (lg * 4 + r));                             \
        _Pragma("unroll") for (int i = 0; i < 8; ++i)                                    \
          _Pragma("unroll") for (int r = 0; r < 4; ++r) o[i][r] *= ar[r];                \
      }                                                                                  \
      float p[4][4]; float psum = 0.f;                                                   \
      _Pragma("unroll") for (int cb = 0; cb < 4; ++cb)                                   \
        _Pragma("unroll") for (int r = 0; r < 4; ++r) {                                  \
          p[cb][r] = exp2f(sl[cb][r] - mrow); psum += p[cb][r];                          \
        }                                                                                \
      psum += __shfl_xor(psum, 16);                                                      \
      psum += __shfl_xor(psum, 32);                                                      \
      lrow += psum;                                                                      \
      bf16x8 pa0, pa1;                                                                   \
      _Pragma("unroll") for (int r = 0; r < 4; ++r) {                                    \
        pa0[r] = (bf16)p[0][r]; pa0[4 + r] = (bf16)p[1][r];                              \
        pa1[r] = (bf16)p[2][r]; pa1[4 + r] = (bf16)p[3][r];                              \
      }                                                                                  \
      __builtin_amdgcn_s_setprio(1);                                                     \
      _Pragma("unroll") for (int db = 0; db < 8; ++db) {                                 \
        bf16x8 vf0 = *reinterpret_cast<const bf16x8*>(Vt[bufb] + (db*16+lm)*PADV + lg*8);\
        bf16x8 vf1 = *reinterpret_cast<const bf16x8*>(Vt[bufb] + (db*16+lm)*PADV + 32 + lg*8);\
        o[db] = __builtin_amdgcn_mfma_f32_16x16x32_bf16(pa0, vf0, o[db], 0, 0, 0);       \
        o[db] = __builtin_amdgcn_mfma_f32_16x16x32_bf16(pa1, vf1, o[db], 0, 0, 0);       \
      }                                                                                  \
      __builtin_amdgcn_s_setprio(0);                                                     \
    } }

__global__ __launch_bounds__(512, 4) void attn_kernel(const bf16* __restrict__ qkv,
                                                      bf16* __restrict__ out,
                                                      const float* __restrict__ wo,
                                                      bf16* __restrict__ wob) {
  __shared__ __align__(16) bf16 Ks[2][64 * 128];
  __shared__ __align__(16) bf16 Vt[2][128 * PADV];

  const int bx = blockIdx.x;
  // balanced CU pairing: block c (c<256) gets qt=15-(c>>5), block c+256 gets qt=(c>>5)
  const int qt = (bx < 256) ? (15 - (bx >> 5)) : ((bx - 256) >> 5);
  const int h = bx & 31;                // head -> fixed XCD: KV L2 locality
  const int kvh = h >> 2;               // GROUPS = 4
  const int q0 = qt * 128;
  const int t = threadIdx.x, lane = t & 63, w = t >> 6;   // 8 waves
  const int lg = lane >> 4, lm = lane & 15;
  const int dchunk = t >> 5, kv2 = t & 31;
  const int kva = kv2 * 2;
  const int k5 = kva & 31;
  const int slot = ((kva >> 5) << 5) | (((k5 >> 2) & 3) << 3) | ((k5 >> 4) << 2) | (k5 & 3);
  const bf16* kbase = qkv + K_COL + kvh * HD;
  const bf16* vbase = qkv + V_COL + kvh * HD;

  const long qrow = q0 + w * 16 + lm;
  const int qg = q0 + w * 16 + lm;
  bf16x8 qf[4];
#pragma unroll
  for (int ks = 0; ks < 4; ++ks)
    qf[ks] = *reinterpret_cast<const bf16x8*>(qkv + qrow * QKV_N + h * HD + ks * 32 + lg * 8);

  f32x4 o[8];
#pragma unroll
  for (int i = 0; i < 8; ++i) o[i] = f32x4{0.f, 0.f, 0.f, 0.f};
  float mrow = -1e30f, lrow = 0.f;

  const int nst = 2 * qt + 2;
  bf16x8 va0, va1, vb0, vb1;

  // ---- prologue ----
  AK_ISSUEK(0, 0);
  AK_ISSUEV(0, va0, va1);
  AK_WRITEV(va0, va1, 0);
  AK_ISSUEV(64, vb0, vb1);
  asm volatile("s_waitcnt lgkmcnt(0)" ::: "memory");
  __builtin_amdgcn_s_barrier();

  for (int I = 0; I < (nst >> 1); ++I) {
    const int s0 = 2 * I;
    AK_ISSUEK((s0 + 1) * 64, 1);
    AK_ISSUEV((s0 + 2) * 64, va0, va1);
    AK_WRITEV(vb0, vb1, 1);
    AK_STEP(s0, 0);
    AK_BAR();
    AK_ISSUEK((s0 + 2) * 64, 0);
    AK_ISSUEV((s0 + 3) * 64, vb0, vb1);
    AK_WRITEV(va0, va1, 0);
    AK_STEP(s0 + 1, 1);
    AK_BAR();
  }

  // ---- epilogue: normalize + store ----
  float invr[4];
#pragma unroll
  for (int r = 0; r < 4; ++r)
    invr[r] = 1.0f / __shfl(lrow, (lane & 48) | (lg * 4 + r));
#pragma unroll
  for (int r = 0; r < 4; ++r) {
    long row = q0 + w * 16 + lg * 4 + r;
#pragma unroll
    for (int db = 0; db < 8; ++db)
      out[row * HID_DIM + h * HD + db * 16 + lm] = (bf16)(o[db][r] * invr[r]);
  }

  // ---- tail: convert Wo fp32->bf16 (4096x4096), 8192 float4 per block ----
  {
    const float4* wsrc = reinterpret_cast<const float4*>(wo);
    bf16x4* wdst = reinterpret_cast<bf16x4*>(wob);
    long base = (long)bx * 8192 + t;    // 512 blocks x 512 threads x 16 iters
#pragma unroll
    for (int it = 0; it < 16; ++it) {
      float4 v = wsrc[base + it * 512];
      bf16x4 o4;
      o4[0] = (bf16)v.x; o4[1] = (bf16)v.y; o4[2] = (bf16)v.z; o4[3] = (bf16)v.w;
      wdst[base + it * 512] = o4;
    }
  }
}

extern "C" void kernel_launch(void* const* d_in, const int* in_sizes, int n_in,
                              void* d_out, int out_size, void* d_ws, size_t ws_size,
                              hipStream_t stream) {
  const float* hs = (const float*)d_in[0];
  const float* Wq = (const float*)d_in[1];
  const float* Wk = (const float*)d_in[2];
  const float* Wv = (const float*)d_in[3];
  const float* Wo = (const float*)d_in[4];
  float* out = (float*)d_out;
  char* ws = (char*)d_ws;

  bf16*   hsb   = (bf16*)(ws);                    // 2048x4096 bf16
  bf16*   wqkvb = (bf16*)(ws + 16777216);         // 6144x4096 bf16
  bf16*   wob   = (bf16*)(ws + 67108864);         // 4096x4096 bf16
  bf16*   qkv   = (bf16*)(ws + 100663296);        // 2048x6144 bf16
  bf16*   attn  = (bf16*)(ws + 125829120);        // 2048x4096 bf16
  float2* csf   = (float2*)(ws + 142606336);      // 2048x64 float2 (cos,sin)

  cvt_all_kernel<<<33280, 256, 0, stream>>>(hs, Wq, Wk, Wv, hsb, wqkvb, csf);
  gemm4p_kernel<3, true, bf16><<<dim3(32, 8), 512, 0, stream>>>(hsb, wqkvb, qkv, 2048, 6144, 4096, csf);
  attn_kernel<<<512, 512, 0, stream>>>(qkv, attn, Wo, wob);
  gemm4p_kernel<2, false, float><<<dim3(32, 8), 512, 0, stream>>>(attn, wob, out, 2048, 4096, 4096, nullptr);
}